// Round 8
// baseline (225.981 us; speedup 1.0000x reference)
//
#include <hip/hip_runtime.h>
#include <hip/hip_fp16.h>

__device__ __forceinline__ float2 cadd(float2 a, float2 b) { return make_float2(a.x + b.x, a.y + b.y); }
__device__ __forceinline__ float2 csub(float2 a, float2 b) { return make_float2(a.x - b.x, a.y - b.y); }
__device__ __forceinline__ float2 cmul(float2 w, float2 z) {
    return make_float2(w.x * z.x - w.y * z.y, w.x * z.y + w.y * z.x);
}
__device__ __forceinline__ unsigned pk(float2 z) {
    __half2 h = __floats2half2_rn(z.x, z.y);
    return *reinterpret_cast<unsigned*>(&h);
}
__device__ __forceinline__ float2 upk(unsigned u) {
    __half2 h = *reinterpret_cast<__half2*>(&u);
    return __half22float2(h);
}
__device__ __forceinline__ void bf(float2& lo, float2& hi, float2 w) {
    const float2 p = cmul(w, hi);
    hi = csub(lo, p);
    lo = cadd(lo, p);
}

__host__ __device__ constexpr unsigned crev(unsigned x, int bits) {
    unsigned r = 0;
    for (int k = 0; k < bits; ++k) r |= ((x >> k) & 1u) << (bits - 1 - k);
    return r;
}

// Butterfly network (DIF):
//   stage t (0..22): pairs (i, i + 2^(22-t)); z'[i] = z[i] + w*z[i+D]; z'[i+D] = z[i] - w*z[i+D]
//   w = weight[ bitrev_t(i >> (23-t)) * 2^(22-t) ];  final: out[rev23(i)] = z[i]
// v8 = TWO passes (pass count is the only lever left; each extra pass costs a 64MB round trip):
//   pass1: t=0..11 (bits 22..11 = G). Block = 4096 G x 8 cols. Register phases
//          (0-4 over G[11:7], 5-9 over G[6:2], 10-11 over G[1:0]) + two packed-fp16 LDS
//          exchanges (pitch 9). fp32 in -> fp16 out (the ONLY intermediate rounding).
//   pass2: t=12..22 (bits 10..0). 2048-pt chunks; 8 bitrev-selected chunks/block
//          (rev12(P)=h0*8+lm) in fp32 LDS pitch 2052; 5 radix-4 rounds + radix-2;
//          dense 64B-line bitrev stores (proven pass_c pattern scaled 13->12 bits).

__global__ __launch_bounds__(1024) void fft_pass1(const float* __restrict__ in,
                                                  const float2* __restrict__ wt,
                                                  unsigned* __restrict__ outp)
{
    extern __shared__ unsigned LD[];     // 4096 * 9 uints = 147,456 B
    const int tid  = threadIdx.x;
    const int col0 = blockIdx.x << 3;    // 8 columns (l) per block
    const int c    = tid & 7;            // column within block (all phases)

    float2 X[32];

    // ---- phase A: stages 0..4 over G[11:7]; thread (f = G[6:0], c) ----
    const int f = tid >> 3;              // 0..127
    {
        const size_t base = ((size_t)f << 11) + (size_t)(col0 + c);
#pragma unroll
        for (int a = 0; a < 32; ++a)
            X[a] = make_float2(in[base + ((size_t)a << 18)], 0.f);
    }
#pragma unroll
    for (int s = 0; s < 5; ++s) {
        const int half = 1 << (4 - s);
#pragma unroll
        for (int j = 0; j < 16; ++j) {
            const int mh = j >> (4 - s);
            const int lo = (mh << (5 - s)) | (j & (half - 1));
            const int hi = lo | half;
            bf(X[lo], X[hi], wt[crev((unsigned)mh, s) << (22 - s)]);
        }
    }
    // exchange 1: LD[G*9+c], G = (a<<7)|f
#pragma unroll
    for (int a = 0; a < 32; ++a)
        LD[(((a << 7) | f) * 9) + c] = pk(X[a]);
    __syncthreads();

    // ---- phase B: stages 5..9 over G[6:2]; thread (at=G[11:7], d=G[1:0], c) ----
    const int at = tid >> 5;             // 0..31
    const int d  = (tid >> 3) & 3;       // 0..3
    const unsigned ra = __brev((unsigned)at) >> 27;   // rev5(at)
#pragma unroll
    for (int b = 0; b < 32; ++b)
        X[b] = upk(LD[(((at << 7) | (b << 2) | d) * 9) + c]);
#pragma unroll
    for (int s = 0; s < 5; ++s) {
        const int half = 1 << (4 - s);
#pragma unroll
        for (int j = 0; j < 16; ++j) {
            const int mh = j >> (4 - s);
            const int lo = (mh << (5 - s)) | (j & (half - 1));
            const int hi = lo | half;
            bf(X[lo], X[hi], wt[((crev((unsigned)mh, s) << 5) | ra) << (17 - s)]);
        }
    }
    // exchange 2: write back to the same slots this thread read (unique owner -> no pre-barrier)
#pragma unroll
    for (int b = 0; b < 32; ++b)
        LD[(((at << 7) | (b << 2) | d) * 9) + c] = pk(X[b]);
    __syncthreads();

    // ---- phase C: stages 10..11 over G[1:0]; thread (at, bl=G[3:2], c); regs (dd:2|bh:3) ----
    const int bl = (tid >> 3) & 3;
#pragma unroll
    for (int dd = 0; dd < 4; ++dd)
#pragma unroll
        for (int bh = 0; bh < 8; ++bh)
            X[(dd << 3) | bh] = upk(LD[(((at << 7) | (bh << 4) | (bl << 2) | dd) * 9) + c]);
    // stage 10: flips G-bit1 -> pairs (dd, dd^2); twiddle indep of dd
#pragma unroll
    for (int bh = 0; bh < 8; ++bh) {
        const unsigned b5 = (unsigned)((bh << 2) | bl);
        const float2 w = wt[(((__brev(b5) >> 27) << 5) | ra) << 12];
        bf(X[bh],      X[16 + bh], w);
        bf(X[8 + bh],  X[24 + bh], w);
    }
    // stage 11: flips G-bit0 -> pairs (dd, dd^1); twiddle depends on d1 = dd>>1
#pragma unroll
    for (int d1 = 0; d1 < 2; ++d1)
#pragma unroll
        for (int bh = 0; bh < 8; ++bh) {
            const unsigned b5 = (unsigned)((bh << 2) | bl);
            const float2 w = wt[((((unsigned)d1) << 10) | ((__brev(b5) >> 27) << 5) | ra) << 11];
            bf(X[(d1 << 4) | bh], X[(d1 << 4) | 8 | bh], w);
        }
    // store fp16 packed, natural order
#pragma unroll
    for (int dd = 0; dd < 4; ++dd)
#pragma unroll
        for (int bh = 0; bh < 8; ++bh) {
            const size_t G = (size_t)((at << 7) | (bh << 4) | (bl << 2) | dd);
            outp[(G << 11) + (size_t)(col0 + c)] = pk(X[(dd << 3) | bh]);
        }
}

__global__ __launch_bounds__(1024) void fft_pass2(const unsigned* __restrict__ inp,
                                                  const float2* __restrict__ wt,
                                                  float2* __restrict__ out)
{
    extern __shared__ float2 L[];        // 8 * 2052 float2 = 131,328 B
    const int tid = threadIdx.x;
    const int h0  = blockIdx.x;          // 0..511
    const int lam = tid & 7;             // chunk slot for butterflies
    const int bq  = tid >> 3;            // 0..127
    const unsigned rP = (unsigned)((h0 << 3) | lam);   // rev12(P) for this lane's chunk

    // ---- load: chunk slot cs holds P = rev12(h0*8+cs); 2048 packed fp16 contiguous ----
    {
        const int cs = tid >> 7, fq = tid & 127;
        const unsigned P = __brev((unsigned)((h0 << 3) | cs)) >> 20;
        const uint4* in4 = reinterpret_cast<const uint4*>(inp);
        const size_t gb = ((size_t)P << 9);            // 512 uint4 per chunk
#pragma unroll
        for (int k = 0; k < 4; ++k) {
            const int slot = (k << 7) | fq;
            const uint4 v = in4[gb + slot];
            const int basei = cs * 2052 + (slot << 2);
            L[basei]     = upk(v.x);
            L[basei + 1] = upk(v.y);
            L[basei + 2] = upk(v.z);
            L[basei + 3] = upk(v.w);
        }
    }
    __syncthreads();

    // ---- 5 radix-4 rounds: stages (12,13)..(20,21) ----
#pragma unroll
    for (int rho = 0; rho < 5; ++rho) {
        const int sh = 9 - (rho << 1);   // 9,7,5,3,1
        const int Q  = 1 << sh;
        const int H2 = Q << 1;
#pragma unroll
        for (int k = 0; k < 4; ++k) {
            const int qi = (k << 7) | bq;                 // 0..511
            const int x  = ((qi >> sh) << (sh + 2)) | (qi & (Q - 1));
            const unsigned ar = (unsigned)(x >> (sh + 2));           // 2*rho bits
            const unsigned xr = rho ? (__brev(ar) >> (32 - (rho << 1))) : 0u;
            const unsigned e  = ((xr << 12) | rP) << sh;
            const float2 w1  = wt[e << 1];
            const float2 w2a = wt[e];
            const float2 w2b = wt[e + (1u << 21)];
            const int iA = lam * 2052 + x;
            const float2 A  = L[iA];
            const float2 Bv = L[iA + Q];
            const float2 Cv = L[iA + H2];
            const float2 Dv = L[iA + H2 + Q];
            const float2 pC = cmul(w1, Cv), pD = cmul(w1, Dv);
            const float2 tA = cadd(A, pC),  tC = csub(A, pC);
            const float2 tB = cadd(Bv, pD), tD = csub(Bv, pD);
            const float2 p2 = cmul(w2a, tB);
            const float2 p3 = cmul(w2b, tD);
            L[iA]           = cadd(tA, p2);
            L[iA + Q]       = csub(tA, p2);
            L[iA + H2]      = cadd(tC, p3);
            L[iA + H2 + Q]  = csub(tC, p3);
        }
        __syncthreads();
    }

    // ---- final radix-2 stage (t=22, dist 1): 1024 pairs/chunk -> 8 per thread ----
#pragma unroll
    for (int k = 0; k < 8; ++k) {
        const int pq = (k << 7) | bq;                     // 0..1023
        const int iA = lam * 2052 + (pq << 1);
        const unsigned e = ((__brev((unsigned)pq) >> 22) << 12) | rP;
        const float2 w = wt[e];
        const float2 A  = L[iA];
        const float2 Bv = L[iA + 1];
        const float2 p  = cmul(w, Bv);
        L[iA]     = cadd(A, p);
        L[iA + 1] = csub(A, p);
    }
    __syncthreads();

    // ---- dense store: out[rev11(x)<<12 | h0*8+lm]; 8 lm = one 64B line, float4 per lm-pair ----
    {
        const int l2 = (tid & 3) << 1;   // 0,2,4,6
        const int xb = tid >> 2;         // 0..255
#pragma unroll
        for (int k = 0; k < 8; ++k) {
            const int x = (k << 8) | xb;                  // 0..2047
            const unsigned rx = __brev((unsigned)x) >> 21;   // rev11(x)
            const float2 a0 = L[l2 * 2052 + x];
            const float2 a1 = L[(l2 + 1) * 2052 + x];
            const size_t o = ((size_t)rx << 12) | (size_t)((h0 << 3) | l2);
            *reinterpret_cast<float4*>(out + o) = make_float4(a0.x, a0.y, a1.x, a1.y);
        }
    }
}

extern "C" void kernel_launch(void* const* d_in, const int* in_sizes, int n_in,
                              void* d_out, int out_size, void* d_ws, size_t ws_size,
                              hipStream_t stream)
{
    (void)in_sizes; (void)n_in; (void)out_size; (void)ws_size;
    const float*  in = (const float*)d_in[0];
    const float2* wt = (const float2*)d_in[1];
    float2* outc = (float2*)d_out;
    unsigned* buf1 = (unsigned*)d_ws;    // 32 MB packed fp16

    static bool attr_done = false;
    if (!attr_done) {
        (void)hipFuncSetAttribute(reinterpret_cast<const void*>(fft_pass1),
                                  hipFuncAttributeMaxDynamicSharedMemorySize, 4096 * 9 * 4);
        (void)hipFuncSetAttribute(reinterpret_cast<const void*>(fft_pass2),
                                  hipFuncAttributeMaxDynamicSharedMemorySize, 8 * 2052 * 8);
        attr_done = true;
    }

    fft_pass1<<<256, 1024, 4096 * 9 * 4, stream>>>(in, wt, buf1);    // t=0..11 : in  -> buf1
    fft_pass2<<<512, 1024, 8 * 2052 * 8, stream>>>(buf1, wt, outc);  // t=12..22: buf1 -> out
}